// Round 10
// baseline (325.393 us; speedup 1.0000x reference)
//
#include <hip/hip_runtime.h>

typedef __bf16 bf16_t;
typedef __bf16 bf16x8 __attribute__((ext_vector_type(8)));
typedef __bf16 bf16x4 __attribute__((ext_vector_type(4)));
typedef float f32x4 __attribute__((ext_vector_type(4)));
typedef unsigned int u32;

#define AS1 __attribute__((address_space(1)))
#define AS3 __attribute__((address_space(3)))

#define ASTR 72   // attention P LDS row stride (elems): 144B rows, 16B aligned

#if __has_builtin(__builtin_amdgcn_exp2f)
#define EXP2(x) __builtin_amdgcn_exp2f(x)
#else
#define EXP2(x) exp2f(x)
#endif

// direct global->LDS, 16B per lane; LDS dest = wave-uniform base + lane*16
__device__ __forceinline__ void g2l16(const bf16_t* g, bf16_t* l) {
  __builtin_amdgcn_global_load_lds((const AS1 u32*)g, (AS3 u32*)l, 16, 0, 0);
}

// pack two f32 -> packed bf16 pair (round-half-up; inputs finite >= 0 here)
__device__ __forceinline__ u32 pkbf(float a, float b) {
  u32 ua = __builtin_bit_cast(u32, a) + 0x8000u;
  u32 ub = __builtin_bit_cast(u32, b) + 0x8000u;
  return (ua >> 16) | (ub & 0xFFFF0000u);
}

// ---------------------------------------------------------------------------
// fp32 -> bf16 bulk convert for x, Wq, Wk, Wv, Wo (one dispatch, 1024 elems/blk)
// ---------------------------------------------------------------------------
__global__ __launch_bounds__(256) void cvt5(
    const float* __restrict__ s0, const float* __restrict__ s1,
    const float* __restrict__ s2, const float* __restrict__ s3,
    const float* __restrict__ s4,
    bf16_t* __restrict__ d0, bf16_t* __restrict__ d1, bf16_t* __restrict__ d2,
    bf16_t* __restrict__ d3, bf16_t* __restrict__ d4)
{
  int blk = blockIdx.x;
  const float* s; bf16_t* d; int off;
  if      (blk <  8192) { s = s0; d = d0; off = blk;         }  // x : 8388608
  else if (blk < 12288) { s = s1; d = d1; off = blk -  8192; }  // Wq: 4194304
  else if (blk < 13312) { s = s2; d = d2; off = blk - 12288; }  // Wk: 1048576
  else if (blk < 14336) { s = s3; d = d3; off = blk - 13312; }  // Wv: 1048576
  else                  { s = s4; d = d4; off = blk - 14336; }  // Wo: 4194304
  size_t i = (size_t)off * 1024 + threadIdx.x * 4;
  float4 v = *(const float4*)&s[i];
  bf16x4 t;
  t[0] = (bf16_t)v.x; t[1] = (bf16_t)v.y; t[2] = (bf16_t)v.z; t[3] = (bf16_t)v.w;
  *(bf16x4*)&d[i] = t;
}

// ---------------------------------------------------------------------------
// GEMM core v2: BK=32, double-buffered single-barrier pipelined K-loop,
// XOR-chunk swizzle (conflict-free, verified R9: SQ_LDS_BANK_CONFLICT = 0).
// ---------------------------------------------------------------------------
__device__ __forceinline__ void gemm_core(
    const bf16_t* __restrict__ A, const bf16_t* __restrict__ B, int K,
    bf16_t* As0, bf16_t* As1, bf16_t* Bs0, bf16_t* Bs1, f32x4 (&acc)[4][4])
{
  const int tid = threadIdx.x, lane = tid & 63, w = tid >> 6;
  const int col = lane & 15, quad = lane >> 4;
  const int wm = w >> 1, wn = w & 1;
  const int lr = lane >> 2;
  const int lc = (((lane & 3) ^ ((lane >> 3) & 3)) << 3);  // swizzled stage chunk
  const int sw = ((quad ^ ((col >> 1) & 3)) << 3);         // swizzled read chunk
  const bf16_t* ga = A + (size_t)(w * 16 + lr) * K + lc;
  const bf16_t* gb = B + (size_t)(w * 16 + lr) * K + lc;
  const int lo0 = (w * 16) * 32, lo1 = (64 + w * 16) * 32;  // wave-uniform LDS bases

  // prologue: stage kb=0 into buffer 0
  g2l16(ga,                  As0 + lo0);
  g2l16(ga + (size_t)64 * K, As0 + lo1);
  g2l16(gb,                  Bs0 + lo0);
  g2l16(gb + (size_t)64 * K, Bs0 + lo1);

  const int nkb = K >> 5;
  for (int kb = 0; kb < nkb; ++kb) {
    __syncthreads();   // vmcnt(0): stage(kb) visible; prior reads of next buf done
    bf16_t* Ac = (kb & 1) ? As1 : As0;
    bf16_t* Bc = (kb & 1) ? Bs1 : Bs0;
    if (kb + 1 < nkb) {   // prefetch kb+1 into the other buffer
      bf16_t* An = (kb & 1) ? As0 : As1;
      bf16_t* Bn = (kb & 1) ? Bs0 : Bs1;
      const int k2 = (kb + 1) * 32;
      g2l16(ga + k2,                  An + lo0);
      g2l16(ga + k2 + (size_t)64 * K, An + lo1);
      g2l16(gb + k2,                  Bn + lo0);
      g2l16(gb + k2 + (size_t)64 * K, Bn + lo1);
    }

    bf16x8 af[4], bfr[4];
#pragma unroll
    for (int mt = 0; mt < 4; ++mt)
      af[mt] = *(const bf16x8*)&Ac[(wm * 64 + mt * 16 + col) * 32 + sw];
#pragma unroll
    for (int nt = 0; nt < 4; ++nt)
      bfr[nt] = *(const bf16x8*)&Bc[(wn * 64 + nt * 16 + col) * 32 + sw];
#pragma unroll
    for (int mt = 0; mt < 4; ++mt)
#pragma unroll
      for (int nt = 0; nt < 4; ++nt)
        acc[mt][nt] = __builtin_amdgcn_mfma_f32_16x16x32_bf16(af[mt], bfr[nt], acc[mt][nt], 0, 0, 0);
  }
}

// ---------------------------------------------------------------------------
// merged QKV projection with FUSED RMSNorm+RoPE (Q,K) and FUSED V-TRANSPOSE.
// bn 0..15 -> Q, 16..19 -> K, 20..23 -> V (direct transposed store to Vt).
// ---------------------------------------------------------------------------
__global__ __launch_bounds__(256, 4) void gemm_qkv(
    const bf16_t* __restrict__ xb, const bf16_t* __restrict__ Wqb,
    const bf16_t* __restrict__ Wkb, const bf16_t* __restrict__ Wvb,
    const float* __restrict__ cosT, const float* __restrict__ sinT,
    const float* __restrict__ wq, const float* __restrict__ wk,
    bf16_t* __restrict__ Qn, bf16_t* __restrict__ Kn, bf16_t* __restrict__ Vt)
{
  __shared__ bf16_t As[2][128 * 32], Bs[2][128 * 32];
  const int bn = blockIdx.x, bm = blockIdx.y;
  const bf16_t* B;
  if      (bn < 16) B = Wqb + (size_t)bn * 128 * 2048;
  else if (bn < 20) B = Wkb + (size_t)(bn - 16) * 128 * 2048;
  else              B = Wvb + (size_t)(bn - 20) * 128 * 2048;

  f32x4 acc[4][4] = {};
  gemm_core(xb + (size_t)bm * 128 * 2048, B, 2048, As[0], As[1], Bs[0], Bs[1], acc);

  const int lane = threadIdx.x & 63, w = threadIdx.x >> 6;
  const int col = lane & 15, quad = lane >> 4, wm = w >> 1, wn = w & 1;

  if (bn < 20) {  // Q or K: fused RMSNorm + RoPE, head-major output
    const bool isQ = bn < 16;
    const float* wnv = isQ ? wq : wk;
    float w4[4];
#pragma unroll
    for (int nt = 0; nt < 4; ++nt) w4[nt] = wnv[nt * 16 + col];
    bf16_t* dst = isQ ? Qn + ((size_t)(bn * 2 + wn)) * 2048 * 64
                      : Kn + ((size_t)((bn - 16) * 2 + wn)) * 2048 * 64;
    const size_t bstride = isQ ? (size_t)32 * 2048 * 64 : (size_t)8 * 2048 * 64;
    const float qscale = 0.125f * 1.4426950408889634f;  // SCALE * log2(e)

#pragma unroll
    for (int mt = 0; mt < 4; ++mt)
#pragma unroll
      for (int r = 0; r < 4; ++r) {
        int row = bm * 128 + wm * 64 + mt * 16 + quad * 4 + r;
        int b = row >> 11, s = row & 2047;
        float v[4], ss = 0.f;
#pragma unroll
        for (int nt = 0; nt < 4; ++nt) { v[nt] = acc[mt][nt][r]; ss += v[nt] * v[nt]; }
        ss += __shfl_xor(ss, 1, 64);
        ss += __shfl_xor(ss, 2, 64);
        ss += __shfl_xor(ss, 4, 64);
        ss += __shfl_xor(ss, 8, 64);
        float rr = rsqrtf(ss * (1.0f / 64.0f) + 1e-6f);
        float t[4];
#pragma unroll
        for (int nt = 0; nt < 4; ++nt) t[nt] = v[nt] * rr * w4[nt];
        bf16_t* drow = dst + b * bstride + (size_t)s * 64;
#pragma unroll
        for (int nt = 0; nt < 4; ++nt) {
          int hd = nt * 16 + col;
          float rot = (nt < 2) ? -t[nt + 2] : t[nt - 2];
          float ov = t[nt] * cosT[s * 64 + hd] + rot * sinT[s * 64 + hd];
          if (isQ) ov *= qscale;
          drow[hd] = (bf16_t)ov;
        }
      }
  } else {        // V: direct transposed store -> Vt [B,KVH,HD=64,S=2048]
    const int kvh = (bn - 20) * 2 + wn;
#pragma unroll
    for (int mt = 0; mt < 4; ++mt) {
      int row0 = bm * 128 + wm * 64 + mt * 16 + quad * 4;   // token of r=0
      int b = row0 >> 11, s0 = row0 & 2047;                 // r stays in-batch
#pragma unroll
      for (int nt = 0; nt < 4; ++nt) {
        bf16x4 t;
#pragma unroll
        for (int r = 0; r < 4; ++r) t[r] = (bf16_t)acc[mt][nt][r];
        *(bf16x4*)&Vt[(((size_t)(b * 8 + kvh)) * 64 + nt * 16 + col) * 2048 + s0] = t;
      }
    }
  }
}

// output projection: A = Ao bf16 [4096,2048], B = Wob bf16, C = out fp32
__global__ __launch_bounds__(256, 4) void gemm_o(
    const bf16_t* __restrict__ Ao, const bf16_t* __restrict__ Wob,
    float* __restrict__ Cf)
{
  __shared__ bf16_t As[2][128 * 32], Bs[2][128 * 32];
  const int bn = blockIdx.x, bm = blockIdx.y;
  f32x4 acc[4][4] = {};
  gemm_core(Ao + (size_t)bm * 128 * 2048, Wob + (size_t)bn * 128 * 2048, 2048,
            As[0], As[1], Bs[0], Bs[1], acc);

  const int lane = threadIdx.x & 63, w = threadIdx.x >> 6;
  const int col = lane & 15, quad = lane >> 4, wm = w >> 1, wn = w & 1;
#pragma unroll
  for (int mt = 0; mt < 4; ++mt)
#pragma unroll
    for (int r = 0; r < 4; ++r) {
      int row = bm * 128 + wm * 64 + mt * 16 + quad * 4 + r;
      float* crow = Cf + (size_t)row * 2048 + bn * 128 + wn * 64 + col;
#pragma unroll
      for (int nt = 0; nt < 4; ++nt)
        crow[nt * 16] = acc[mt][nt][r];
    }
}

// ---------------------------------------------------------------------------
// Flash attention v8: 2 sibling GQA heads per block -> K/V staging AND K/V
// fragment registers shared across heads (DS-cycles/FLOP -1.45x, K/V fetch
// halved).  Software-pipelined single-barrier K-loop (R8), qt-descending LPT.
// P round-trips per-head through the same Ps scratch; V frags stay resident.
// ---------------------------------------------------------------------------
__global__ __launch_bounds__(256, 2) void attn(
    const bf16_t* __restrict__ Qn, const bf16_t* __restrict__ Kn,
    const bf16_t* __restrict__ Vt, bf16_t* __restrict__ Ao)
{
  __shared__ bf16_t KsL[2][64 * 32], KsH[2][64 * 32];   // K tile halves x2 buf
  __shared__ bf16_t VsL[2][64 * 32], VsH[2][64 * 32];   // V^T tile halves x2 buf
  __shared__ bf16_t Ps[128 * ASTR];                     // 4 waves x 32 rows
  // total LDS = 32768 + 18432 = 51200 B

  const int tid = threadIdx.x, lane = tid & 63, w = tid >> 6;
  const int col = lane & 15, quad = lane >> 4;
  const int lr = lane >> 2;
  const int lcs = (((lane & 3) ^ ((lane >> 3) & 3)) << 3);  // swizzled stage chunk
  const int sw  = ((quad ^ ((col >> 1) & 3)) << 3);         // swizzled read chunk
  const int hp = blockIdx.x, b = blockIdx.y;
  const int qt = 15 - blockIdx.z;         // qt slowest dim, descending (LPT)
  const int h0 = hp * 2;
  const int kvh = h0 >> 2;

  const bf16_t* Kb = Kn + ((size_t)(b * 8 + kvh)) * 2048 * 64;
  const bf16_t* Vb = Vt + ((size_t)(b * 8 + kvh)) * 64 * 2048;
  const bf16_t* Qb = Qn + (((size_t)(b * 32 + h0)) * 2048 + qt * 128) * 64;
  const int lw = w * 512;                 // wave-uniform LDS sub-base

  // Q fragments for both heads (B-operand layout), loaded once
  bf16x8 Qf[2][2][2];   // [hh][mt][kk]
#pragma unroll
  for (int hh = 0; hh < 2; ++hh)
#pragma unroll
    for (int mt = 0; mt < 2; ++mt)
#pragma unroll
      for (int kk = 0; kk < 2; ++kk)
        Qf[hh][mt][kk] = *(const bf16x8*)&Qb[(size_t)hh * 2048 * 64 +
                                             (w * 32 + mt * 16 + col) * 64 + kk * 32 + quad * 8];

  bf16x8 ones;
#pragma unroll
  for (int i = 0; i < 8; ++i) ones[i] = (bf16_t)1.0f;

  f32x4 o[2][2][4] = {};    // [hh][mt][nt]
  f32x4 lacc[2][2] = {};    // [hh][mt]

  const int rowmin = qt * 128 + w * 32;
  const int rowmax = rowmin + 31;
  const int jmax = 2 * qt + 1;

  // prologue: stage tile 0 into buffer 0
  {
    const bf16_t* gk = &Kb[(size_t)(w * 16 + lr) * 64 + lcs];
    const bf16_t* gv = &Vb[(size_t)(w * 16 + lr) * 2048 + lcs];
    g2l16(gk,      &KsL[0][lw]);
    g2l16(gk + 32, &KsH[0][lw]);
    g2l16(gv,      &VsL[0][lw]);
    g2l16(gv + 32, &VsH[0][lw]);
  }

  for (int j = 0; j <= jmax; ++j) {
    __syncthreads();   // vmcnt(0): stage(j) visible; prior compute reads done
    if (j < jmax) {    // prefetch j+1 into the other buffer (block-uniform)
      const int nb = (j + 1) & 1;
      const bf16_t* gk = &Kb[(size_t)((j + 1) * 64 + w * 16 + lr) * 64 + lcs];
      const bf16_t* gv = &Vb[(size_t)(w * 16 + lr) * 2048 + (j + 1) * 64 + lcs];
      g2l16(gk,      &KsL[nb][lw]);
      g2l16(gk + 32, &KsH[nb][lw]);
      g2l16(gv,      &VsL[nb][lw]);
      g2l16(gv + 32, &VsH[nb][lw]);
    }

    if (j * 64 <= rowmax) {     // per-wave compute guard (fully-masked: skip)
      const int bf = j & 1;
      const bool needmask = (j * 64 + 63 > rowmin);

      // ---- S^T = K Q^T for both heads; P cached in regs (f32) ----
      u32 pk[2][2][4][2];   // [hh][mt][kt][2x packed bf16 pair]
#pragma unroll
      for (int kt = 0; kt < 4; ++kt) {
        bf16x8 kf0 = *(const bf16x8*)&KsL[bf][(kt * 16 + col) * 32 + sw];
        bf16x8 kf1 = *(const bf16x8*)&KsH[bf][(kt * 16 + col) * 32 + sw];
        const int k0 = j * 64 + kt * 16 + quad * 4;
#pragma unroll
        for (int hh = 0; hh < 2; ++hh)
#pragma unroll
          for (int mt = 0; mt < 2; ++mt) {
            f32x4 st = {};
            st = __builtin_amdgcn_mfma_f32_16x16x32_bf16(kf0, Qf[hh][mt][0], st, 0, 0, 0);
            st = __builtin_amdgcn_mfma_f32_16x16x32_bf16(kf1, Qf[hh][mt][1], st, 0, 0, 0);
            float p0 = EXP2(st[0]), p1 = EXP2(st[1]);
            float p2 = EXP2(st[2]), p3 = EXP2(st[3]);
            if (needmask) {   // wave-uniform branch (diagonal tiles only)
              const int qg = qt * 128 + w * 32 + mt * 16 + col;
              p0 = (k0 + 0 > qg) ? 0.f : p0;
              p1 = (k0 + 1 > qg) ? 0.f : p1;
              p2 = (k0 + 2 > qg) ? 0.f : p2;
              p3 = (k0 + 3 > qg) ? 0.f : p3;
            }
            pk[hh][mt][kt][0] = pkbf(p0, p1);
            pk[hh][mt][kt][1] = pkbf(p2, p3);
          }
      }

      // ---- V fragments once (shared across heads) ----
      bf16x8 vf[2][4];
#pragma unroll
      for (int kk = 0; kk < 2; ++kk) {
        const bf16_t* Vh = kk ? &VsH[bf][0] : &VsL[bf][0];
#pragma unroll
        for (int nt = 0; nt < 4; ++nt)
          vf[kk][nt] = *(const bf16x8*)&Vh[(nt * 16 + col) * 32 + sw];
      }

      // ---- per-head: P round-trip through Ps, then PV + rowsum ----
#pragma unroll
      for (int hh = 0; hh < 2; ++hh) {
#pragma unroll
        for (int mt = 0; mt < 2; ++mt)
#pragma unroll
          for (int kt = 0; kt < 4; ++kt) {
            uint2 u = { pk[hh][mt][kt][0], pk[hh][mt][kt][1] };
            *(uint2*)&Ps[(w * 32 + mt * 16 + col) * ASTR + kt * 16 + quad * 4] = u;
          }
        asm volatile("s_waitcnt lgkmcnt(0)" ::: "memory");

#pragma unroll
        for (int kk = 0; kk < 2; ++kk) {
          bf16x8 pa0 = *(const bf16x8*)&Ps[(w * 32 + col) * ASTR + kk * 32 + quad * 8];
          bf16x8 pa1 = *(const bf16x8*)&Ps[(w * 32 + 16 + col) * ASTR + kk * 32 + quad * 8];
          lacc[hh][0] = __builtin_amdgcn_mfma_f32_16x16x32_bf16(pa0, ones, lacc[hh][0], 0, 0, 0);
          lacc[hh][1] = __builtin_amdgcn_mfma_f32_16x16x32_bf16(pa1, ones, lacc[hh][1], 0, 0, 0);
#pragma unroll
          for (int nt = 0; nt < 4; ++nt) {
            o[hh][0][nt] = __builtin_amdgcn_mfma_f32_16x16x32_bf16(pa0, vf[kk][nt], o[hh][0][nt], 0, 0, 0);
            o[hh][1][nt] = __builtin_amdgcn_mfma_f32_16x16x32_bf16(pa1, vf[kk][nt], o[hh][1][nt], 0, 0, 0);
          }
        }
        if (hh == 0)   // Ps reused by head 1: drain reads before overwrite
          asm volatile("s_waitcnt lgkmcnt(0)" ::: "memory");
      }
    }
  }

  // epilogue: divide by l, write token-major bf16 [B*S, H*HD], both heads
#pragma unroll
  for (int hh = 0; hh < 2; ++hh)
#pragma unroll
    for (int mt = 0; mt < 2; ++mt)
#pragma unroll
      for (int r = 0; r < 4; ++r) {
        float inv = 1.0f / lacc[hh][mt][r];
        int row = b * 2048 + qt * 128 + w * 32 + mt * 16 + quad * 4 + r;
        bf16_t* orow = &Ao[(size_t)row * 2048 + (h0 + hh) * 64 + col];
#pragma unroll
        for (int nt = 0; nt < 4; ++nt)
          orow[nt * 16] = (bf16_t)(o[hh][mt][nt][r] * inv);
      }
}

// ---------------------------------------------------------------------------
extern "C" void kernel_launch(void* const* d_in, const int* in_sizes, int n_in,
                              void* d_out, int out_size, void* d_ws, size_t ws_size,
                              hipStream_t stream)
{
  const float* x    = (const float*)d_in[0];
  // d_in[1] = mask (unused; causal hardcoded)
  const float* cosT = (const float*)d_in[2];
  const float* sinT = (const float*)d_in[3];
  const float* Wq   = (const float*)d_in[4];
  const float* Wk   = (const float*)d_in[5];
  const float* Wv   = (const float*)d_in[6];
  const float* Wo   = (const float*)d_in[7];
  const float* wq   = (const float*)d_in[8];
  const float* wk   = (const float*)d_in[9];
  float* out = (float*)d_out;

  char* ws = (char*)d_ws;
  bf16_t* xb  = (bf16_t*)(ws);                 // 16777216  until gemm_qkv
  bf16_t* Ao  = (bf16_t*)(ws);                 // (reuses xb) attn -> gemm_o
  bf16_t* Wqb = (bf16_t*)(ws + 16777216);      //  8388608  until gemm_qkv
  bf16_t* Wkb = (bf16_t*)(ws + 25165824);      //  2097152
  bf16_t* Wvb = (bf16_t*)(ws + 27262976);      //  2097152
  bf16_t* Wob = (bf16_t*)(ws + 29360128);      //  8388608  until gemm_o
  bf16_t* Vt  = (bf16_t*)(ws + 37748736);      //  4194304  gemm_qkv -> attn
  bf16_t* Qn  = (bf16_t*)(ws + 41943040);      // 16777216  until attn
  bf16_t* Kn  = (bf16_t*)(ws + 58720256);      //  4194304  until attn
  // total 62914560 B

  cvt5<<<18432, 256, 0, stream>>>(x, Wq, Wk, Wv, Wo, xb, Wqb, Wkb, Wvb, Wob);
  gemm_qkv<<<dim3(24, 32), 256, 0, stream>>>(xb, Wqb, Wkb, Wvb, cosT, sinT, wq, wk, Qn, Kn, Vt);
  attn<<<dim3(16, 2, 16), 256, 0, stream>>>(Qn, Kn, Vt, Ao);
  gemm_o<<<dim3(16, 32), 256, 0, stream>>>(Ao, Wob, out);
}